// Round 5
// baseline (338.118 us; speedup 1.0000x reference)
//
#include <hip/hip_runtime.h>
#include <stdint.h>

typedef __attribute__((ext_vector_type(8))) short bf16x8;
typedef __attribute__((ext_vector_type(4))) float f32x4;

__device__ __forceinline__ ushort f2bf(float f) {
    union { float f; uint32_t i; } v; v.f = f;
    uint32_t r = v.i + 0x7fff + ((v.i >> 16) & 1);
    return (ushort)(r >> 16);
}
__device__ __forceinline__ uint32_t cvtpk(float lo, float hi) {
    uint32_t r;
    asm("v_cvt_pk_bf16_f32 %0, %1, %2" : "=v"(r) : "v"(lo), "v"(hi));
    return r;
}

typedef unsigned int uint_as1 __attribute__((address_space(1)));
typedef unsigned int uint_as3 __attribute__((address_space(3)));
__device__ __forceinline__ void async16(const void* g, void* l) {
    __builtin_amdgcn_global_load_lds((const uint_as1*)g, (uint_as3*)l, 16, 0, 0);
}

// ---------------- small prep kernels ----------------

__global__ void cvt_f32_bf16(const float* __restrict__ in, ushort* __restrict__ out, int n) {
    int i = blockIdx.x * blockDim.x + threadIdx.x;
    if (i < n) out[i] = f2bf(in[i]);
}

__global__ void prep_bn(const float* __restrict__ bk, const float* __restrict__ gamma,
                        const float* __restrict__ beta, const float* __restrict__ rmean,
                        const float* __restrict__ rvar,
                        float* __restrict__ scaleA, float* __restrict__ shiftA) {
    int i = threadIdx.x;  // 256 threads, 1 block
    float s = gamma[i] * rsqrtf(rvar[i] + 1e-5f);
    scaleA[i] = 0.25f * s;                                // fold Ck^-0.5 = 1/16 as 0.25 per operand
    shiftA[i] = 0.25f * ((bk[i] - rmean[i]) * s + beta[i]);
}

// x [b][512][6400] f32  ->  Xt [b][6400][512] bf16
__global__ void transpose_cvt(const float* __restrict__ x, ushort* __restrict__ xt) {
    __shared__ float t[32][33];
    int b = blockIdx.z;
    int n0 = blockIdx.x * 32, c0 = blockIdx.y * 32;
    const float* xb = x + (size_t)b * 512 * 6400;
    ushort* xtb = xt + (size_t)b * 6400 * 512;
    int tx = threadIdx.x, ty = threadIdx.y;
    t[ty][tx] = xb[(size_t)(c0 + ty) * 6400 + n0 + tx];
    __syncthreads();
    xtb[(size_t)(n0 + ty) * 512 + c0 + tx] = f2bf(t[tx][ty]);
}

// ---------------- unified NT GEMM (128x128): C[i][j] = sum_k A[i][k]*B[j][k] ----------------
// Round-4 proven kernel: 4 waves, BK=32, 3-buf LDS, counted vmcnt(4)+raw barrier.
// Used for Kt / V / out (small-N GEMMs). Epilogue stores via v_cvt_pk_bf16_f32.
// EPI 1: bf16 store relu(acc*vec0[col] + vec1[col]) ; EPI 2: bf16 acc+vec0[row]
// EPI 3: f32 acc+vec0[row]
template <int EPI>
__global__ __launch_bounds__(256) void gemm_nt(
    const ushort* __restrict__ A, const ushort* __restrict__ B, void* __restrict__ Cout,
    int K, int lda, int ldb, int ldc,
    size_t zsa, size_t zsb, size_t zsc,
    const float* __restrict__ vec0, const float* __restrict__ vec1) {
    __shared__ __align__(16) ushort smem[6 * 4096];

    A += (size_t)blockIdx.z * zsa;
    B += (size_t)blockIdx.z * zsb;

    const int tid = threadIdx.x;
    const int lane = tid & 63, wave = tid >> 6;
    const int wm = wave & 1, wn = wave >> 1;
    const int bM = blockIdx.y * 128, bN = blockIdx.x * 128;

    const int sr = lane >> 2;
    const int sc = (lane & 3) * 8;
    const ushort* gA0 = A + (size_t)(bM + wave * 32 + sr) * lda + sc;
    const ushort* gA1 = gA0 + (size_t)16 * lda;
    const ushort* gB0 = B + (size_t)(bN + wave * 32 + sr) * ldb + sc;
    const ushort* gB1 = gB0 + (size_t)16 * ldb;
    ushort* lAw = &smem[wave * 1024];
    ushort* lBw = &smem[3 * 4096 + wave * 1024];

    const int rowA = wm * 64;
    const int rowB = wn * 64;
    const int fr = lane & 15;
    const int fk = (lane >> 4) * 8;

    f32x4 acc[4][4] = {};
    const int nT = K >> 5;

    auto stage = [&](int t, int buf) {
        const int k0 = t * 32;
        const int ob = buf * 4096;
        async16(gA0 + k0, lAw + ob);
        async16(gA1 + k0, lAw + ob + 512);
        async16(gB0 + k0, lBw + ob);
        async16(gB1 + k0, lBw + ob + 512);
    };

    stage(0, 0);
    if (nT > 1) stage(1, 1);

    for (int t = 0; t < nT; ++t) {
        if (t + 1 < nT) { asm volatile("s_waitcnt vmcnt(4)" ::: "memory"); }
        else            { asm volatile("s_waitcnt vmcnt(0)" ::: "memory"); }
        __builtin_amdgcn_sched_barrier(0);
        __builtin_amdgcn_s_barrier();
        __builtin_amdgcn_sched_barrier(0);
        if (t + 2 < nT) stage(t + 2, (t + 2) % 3);
        const int cur = t % 3;
        const ushort* lA = &smem[cur * 4096];
        const ushort* lB = &smem[3 * 4096 + cur * 4096];
        bf16x8 af[4], bff[4];
#pragma unroll
        for (int mi = 0; mi < 4; mi++)
            af[mi] = *(const bf16x8*)&lA[(rowA + mi * 16 + fr) * 32 + fk];
#pragma unroll
        for (int ni = 0; ni < 4; ni++)
            bff[ni] = *(const bf16x8*)&lB[(rowB + ni * 16 + fr) * 32 + fk];
#pragma unroll
        for (int mi = 0; mi < 4; mi++)
#pragma unroll
            for (int ni = 0; ni < 4; ni++)
                acc[mi][ni] = __builtin_amdgcn_mfma_f32_16x16x32_bf16(af[mi], bff[ni], acc[mi][ni], 0, 0, 0);
        __builtin_amdgcn_sched_barrier(0);
    }
    __builtin_amdgcn_s_barrier();
    __builtin_amdgcn_sched_barrier(0);

    // ---- epilogue: repack through LDS, store full lines ----
    float* Cf = (float*)Cout + (size_t)blockIdx.z * zsc;
    ushort* Cu = (ushort*)Cout + (size_t)blockIdx.z * zsc;
    float* lt = (float*)smem;          // 32*132*4 = 16896 B
    const int g4 = (lane >> 4) * 4;
    const int cl = lane & 15;
    const int lr = tid >> 3;
    const int ch = tid & 7;

#pragma unroll
    for (int mi = 0; mi < 4; ++mi) {
#pragma unroll
        for (int ni = 0; ni < 4; ++ni) {
            const int lcol = wn * 64 + ni * 16 + cl;
#pragma unroll
            for (int r = 0; r < 4; ++r)
                lt[(wm * 16 + g4 + r) * 132 + lcol] = acc[mi][ni][r];
        }
        __syncthreads();
        {
            const int brow = (lr < 16) ? (mi * 16 + lr) : (64 + mi * 16 + (lr - 16));
            const int grow = bM + brow;
            const int gcol = bN + ch * 16;
            float vv[16];
#pragma unroll
            for (int i = 0; i < 16; i += 4) {
                f32x4 q = *(const f32x4*)&lt[lr * 132 + ch * 16 + i];
                vv[i] = q[0]; vv[i + 1] = q[1]; vv[i + 2] = q[2]; vv[i + 3] = q[3];
            }
            if (EPI == 1) {
#pragma unroll
                for (int i = 0; i < 16; i++)
                    vv[i] = fmaxf(vv[i] * vec0[gcol + i] + vec1[gcol + i], 0.f);
            }
            if (EPI == 2 || EPI == 3) {
                const float rb = vec0[grow];
#pragma unroll
                for (int i = 0; i < 16; i++) vv[i] += rb;
            }
            if (EPI == 3) {
#pragma unroll
                for (int i = 0; i < 16; i += 4) {
                    f32x4 q = { vv[i], vv[i + 1], vv[i + 2], vv[i + 3] };
                    *(f32x4*)&Cf[(size_t)grow * ldc + gcol + i] = q;
                }
            } else {
                uint4 q0 = { cvtpk(vv[0], vv[1]), cvtpk(vv[2], vv[3]),
                             cvtpk(vv[4], vv[5]), cvtpk(vv[6], vv[7]) };
                uint4 q1 = { cvtpk(vv[8], vv[9]), cvtpk(vv[10], vv[11]),
                             cvtpk(vv[12], vv[13]), cvtpk(vv[14], vv[15]) };
                *(uint4*)&Cu[(size_t)grow * ldc + gcol] = q0;
                *(uint4*)&Cu[(size_t)grow * ldc + gcol + 8] = q1;
            }
        }
        __syncthreads();
    }
}

// ---------------- wide NT GEMM (128x256): for S (EPI 5) and PV (EPI 4) ----------------
// 4 waves, wave tile 64x128 (acc[4][8]): 12 ds_read_b128 -> 32 MFMA per K-step
// (+33% MFMA per LDS byte vs 128x128). LDS quarter-swizzle kills bank conflicts:
// slot (row, q) holds global quarter q ^ ((row>>1)&3); applied by pre-swizzling the
// global source of global_load_lds (rule #21) and reading with the matching offset
// (lane-constant, zero per-step cost). 3-buf, 2-deep prefetch, vmcnt(6).
// EPI 4: f32 store raw (split-K partials)
// EPI 5: bf16 store exp(acc); per-row block sums -> rsum[blockIdx.x*6400+row]
template <int EPI>
__global__ __launch_bounds__(256) void gemm_wide(
    const ushort* __restrict__ A, const ushort* __restrict__ B, void* __restrict__ Cout,
    int K, int lda, int ldb, int ldc,
    size_t zsa, size_t zsb, size_t zsc,
    float* __restrict__ rsum) {
    // A: 3 bufs x 128x32 (4096 u) ; B: 3 bufs x 256x32 (8192 u) = 72 KB
    __shared__ __align__(16) ushort smem[3 * 4096 + 3 * 8192];

    A += (size_t)blockIdx.z * zsa;
    B += (size_t)blockIdx.z * zsb;

    const int tid = threadIdx.x;
    const int lane = tid & 63, wave = tid >> 6;
    const int wm = wave & 1, wn = wave >> 1;
    const int bM = blockIdx.y * 128, bN = blockIdx.x * 256;

    const int sr = lane >> 2;                                 // staged row within 16-group
    const int scs = ((lane & 3) ^ ((lane >> 3) & 3)) * 8;     // swizzled source quarter
    const ushort* gA0 = A + (size_t)(bM + wave * 32 + sr) * lda + scs;
    const ushort* gA1 = gA0 + (size_t)16 * lda;
    const ushort* gB0 = B + (size_t)(bN + wave * 64 + sr) * ldb + scs;
    const ushort* gB1 = gB0 + (size_t)16 * ldb;
    const ushort* gB2 = gB0 + (size_t)32 * ldb;
    const ushort* gB3 = gB0 + (size_t)48 * ldb;
    ushort* lAw = &smem[wave * 1024];
    ushort* lBw = &smem[3 * 4096 + wave * 2048];

    const int rowA = wm * 64;
    const int rowB = wn * 128;
    const int fr = lane & 15;
    const int fq = lane >> 4;
    const int fk = (fq ^ ((fr >> 1) & 3)) * 8;                // swizzled quarter read

    f32x4 acc[4][8] = {};
    const int nT = K >> 5;

    auto stage = [&](int t, int buf) {
        const int k0 = t * 32;
        ushort* la = lAw + buf * 4096;
        ushort* lb = lBw + buf * 8192;
        async16(gA0 + k0, la);
        async16(gA1 + k0, la + 512);
        async16(gB0 + k0, lb);
        async16(gB1 + k0, lb + 512);
        async16(gB2 + k0, lb + 1024);
        async16(gB3 + k0, lb + 1536);
    };

    stage(0, 0);
    if (nT > 1) stage(1, 1);

    for (int t = 0; t < nT; ++t) {
        if (t + 1 < nT) { asm volatile("s_waitcnt vmcnt(6)" ::: "memory"); }
        else            { asm volatile("s_waitcnt vmcnt(0)" ::: "memory"); }
        __builtin_amdgcn_sched_barrier(0);
        __builtin_amdgcn_s_barrier();
        __builtin_amdgcn_sched_barrier(0);
        if (t + 2 < nT) stage(t + 2, (t + 2) % 3);
        const int cur = t % 3;
        const ushort* lA = &smem[cur * 4096];
        const ushort* lB = &smem[3 * 4096 + cur * 8192];
        bf16x8 af[4], bff[8];
#pragma unroll
        for (int mi = 0; mi < 4; mi++)
            af[mi] = *(const bf16x8*)&lA[(rowA + mi * 16 + fr) * 32 + fk];
#pragma unroll
        for (int ni = 0; ni < 8; ni++)
            bff[ni] = *(const bf16x8*)&lB[(rowB + ni * 16 + fr) * 32 + fk];
#pragma unroll
        for (int mi = 0; mi < 4; mi++)
#pragma unroll
            for (int ni = 0; ni < 8; ni++)
                acc[mi][ni] = __builtin_amdgcn_mfma_f32_16x16x32_bf16(af[mi], bff[ni], acc[mi][ni], 0, 0, 0);
        __builtin_amdgcn_sched_barrier(0);
    }
    __builtin_amdgcn_s_barrier();
    __builtin_amdgcn_sched_barrier(0);

    // ---- epilogue: strip repack through LDS [32][260], 2 chunks of 16 cols/thread ----
    float* Cf = (float*)Cout + (size_t)blockIdx.z * zsc;
    ushort* Cu = (ushort*)Cout + (size_t)blockIdx.z * zsc;
    float* lt = (float*)smem;          // 32*260*4 = 33280 B <= 73728 B
    const int g4 = fq * 4;
    const int cl = fr;
    const int lr = tid >> 3;           // 0..31
    const int ch = tid & 7;            // chunk: cols ch*16 and 128+ch*16

#pragma unroll
    for (int mi = 0; mi < 4; ++mi) {
#pragma unroll
        for (int ni = 0; ni < 8; ++ni) {
            const int lcol = wn * 128 + ni * 16 + cl;
#pragma unroll
            for (int r = 0; r < 4; ++r)
                lt[(wm * 16 + g4 + r) * 260 + lcol] = acc[mi][ni][r];
        }
        __syncthreads();
        {
            const int brow = (lr < 16) ? (mi * 16 + lr) : (64 + mi * 16 + (lr - 16));
            const int grow = bM + brow;
            float vv[32];
#pragma unroll
            for (int h = 0; h < 2; ++h)
#pragma unroll
                for (int i = 0; i < 16; i += 4) {
                    f32x4 q = *(const f32x4*)&lt[lr * 260 + h * 128 + ch * 16 + i];
                    vv[h * 16 + i] = q[0]; vv[h * 16 + i + 1] = q[1];
                    vv[h * 16 + i + 2] = q[2]; vv[h * 16 + i + 3] = q[3];
                }
            if (EPI == 5) {
                float ssum = 0.f;
#pragma unroll
                for (int i = 0; i < 32; i++) { vv[i] = __expf(vv[i]); ssum += vv[i]; }
                ssum += __shfl_down(ssum, 4, 8);
                ssum += __shfl_down(ssum, 2, 8);
                ssum += __shfl_down(ssum, 1, 8);
                if (ch == 0) rsum[(size_t)blockIdx.x * 6400 + grow] = ssum;
#pragma unroll
                for (int h = 0; h < 2; ++h) {
                    const int gcol = bN + h * 128 + ch * 16;
                    const float* p = &vv[h * 16];
                    uint4 q0 = { cvtpk(p[0], p[1]), cvtpk(p[2], p[3]),
                                 cvtpk(p[4], p[5]), cvtpk(p[6], p[7]) };
                    uint4 q1 = { cvtpk(p[8], p[9]), cvtpk(p[10], p[11]),
                                 cvtpk(p[12], p[13]), cvtpk(p[14], p[15]) };
                    *(uint4*)&Cu[(size_t)grow * ldc + gcol] = q0;
                    *(uint4*)&Cu[(size_t)grow * ldc + gcol + 8] = q1;
                }
            } else {  // EPI 4: f32 raw
#pragma unroll
                for (int h = 0; h < 2; ++h) {
                    const int gcol = bN + h * 128 + ch * 16;
#pragma unroll
                    for (int i = 0; i < 16; i += 4) {
                        f32x4 q = { vv[h * 16 + i], vv[h * 16 + i + 1],
                                    vv[h * 16 + i + 2], vv[h * 16 + i + 3] };
                        *(f32x4*)&Cf[(size_t)grow * ldc + gcol + i] = q;
                    }
                }
            }
        }
        __syncthreads();
    }
}

// ---------------- softmax normalizer: inv[row] = 1 / sum_xb rsum[xb][row] ----------------
__global__ __launch_bounds__(256) void combine_inv(const float* __restrict__ rsum,
                                                   float* __restrict__ inv) {
    int r = blockIdx.x * 256 + threadIdx.x;   // 6400 rows
    float s = 0.f;
#pragma unroll
    for (int xb = 0; xb < 25; xb++) s += rsum[(size_t)xb * 6400 + r];
    inv[r] = 1.f / s;
}

// ---------------- split-K reduce: ctxT bf16 = inv[row] * sum of 10 f32 partial chunks ----------------
__global__ __launch_bounds__(256) void reduce_ctx(const float* __restrict__ part, ushort* __restrict__ ctx,
                                                  const float* __restrict__ inv) {
    const size_t CH = 1638400;  // elems per chunk
    size_t i = ((size_t)blockIdx.x * 256 + threadIdx.x) * 4;
    float4 a = *(const float4*)&part[i];
#pragma unroll
    for (int c = 1; c < 10; c++) {
        float4 s = *(const float4*)&part[i + (size_t)c * CH];
        a.x += s.x; a.y += s.y; a.z += s.z; a.w += s.w;
    }
    const float w = inv[i >> 8];  // 256 cols per row
    uint2 o = { cvtpk(a.x * w, a.y * w), cvtpk(a.z * w, a.w * w) };
    *(uint2*)&ctx[i] = o;
}

// ---------------- host ----------------
extern "C" void kernel_launch(void* const* d_in, const int* in_sizes, int n_in,
                              void* d_out, int out_size, void* d_ws, size_t ws_size,
                              hipStream_t stream) {
    (void)in_sizes; (void)n_in; (void)out_size; (void)ws_size;
    const float* x     = (const float*)d_in[0];
    const float* wk    = (const float*)d_in[1];
    const float* bk    = (const float*)d_in[2];
    const float* gamma = (const float*)d_in[3];
    const float* beta  = (const float*)d_in[4];
    const float* rmean = (const float*)d_in[5];
    const float* rvar  = (const float*)d_in[6];
    const float* wv    = (const float*)d_in[7];
    const float* bv    = (const float*)d_in[8];
    const float* wW    = (const float*)d_in[9];
    const float* bW    = (const float*)d_in[10];
    float* out = (float*)d_out;

    // workspace layout (ushort elements)
    ushort* Xt   = (ushort*)d_ws;          // 2*6400*512   = 6,553,600
    ushort* wkb  = Xt + 6553600;           // 256*512      = 131,072
    ushort* wvb  = wkb + 131072;           // 131,072
    ushort* wWb  = wvb + 131072;           // 512*256      = 131,072
    ushort* Kt   = wWb + 131072;           // 2*6400*256   = 3,276,800
    ushort* V    = Kt + 3276800;           // 3,276,800
    ushort* ctxT = V + 3276800;            // 3,276,800
    ushort* S    = ctxT + 3276800;         // 6400*6400    = 40,960,000 (one batch, reused)
    float* scaleA = (float*)(S + 40960000);
    float* shiftA = scaleA + 256;
    float* rowsum = shiftA + 256;          // 25*6400      = 160,000 f32
    float* inv    = rowsum + 160000;       // 6400 f32
    float* part   = inv + 6400;            // 10*6400*256 f32 = 16,384,000 f32 (65.5 MB)
    // total ~182 MB

    cvt_f32_bf16<<<512, 256, 0, stream>>>(wk, wkb, 131072);
    cvt_f32_bf16<<<512, 256, 0, stream>>>(wv, wvb, 131072);
    cvt_f32_bf16<<<512, 256, 0, stream>>>(wW, wWb, 131072);
    prep_bn<<<1, 256, 0, stream>>>(bk, gamma, beta, rmean, rvar, scaleA, shiftA);
    transpose_cvt<<<dim3(200, 16, 2), dim3(32, 32), 0, stream>>>(x, Xt);

    // Kt[b][n][ck] = relu(affine(Xt . wk^T)), scaled by 0.25  — both batches in one dispatch
    gemm_nt<1><<<dim3(2, 50, 2), 256, 0, stream>>>(Xt, wkb, Kt, 512, 512, 512, 256,
                                                   3276800, 0, 1638400, scaleA, shiftA);
    // V[b][v][m] = wv . Xt^T + bv
    gemm_nt<2><<<dim3(50, 2, 2), 256, 0, stream>>>(wvb, Xt, V, 512, 512, 512, 6400,
                                                   0, 3276800, 1638400, bv, nullptr);

    for (int b = 0; b < 2; b++) {
        ushort* Ktb  = Kt + (size_t)b * 1638400;
        ushort* Vb   = V  + (size_t)b * 1638400;
        ushort* ctxb = ctxT + (size_t)b * 1638400;
        // P_unnorm[n][m] = exp(Kt . Kt^T) (logits already include 1/16); block-row sums to rowsum
        gemm_wide<5><<<dim3(25, 50), 256, 0, stream>>>(Ktb, Ktb, S, 256, 256, 256, 6400,
                                                       0, 0, 0, rowsum);
        combine_inv<<<25, 256, 0, stream>>>(rowsum, inv);
        // ctxT[n][v] = P_unnorm . V^T — split-K x10 into f32 partials (z = k-chunk of 640)
        gemm_wide<4><<<dim3(1, 50, 10), 256, 0, stream>>>(S, Vb, part, 640, 6400, 6400, 256,
                                                          640, 640, 1638400, nullptr);
        reduce_ctx<<<1600, 256, 0, stream>>>(part, ctxb, inv);
    }

    // out[b][o][n] = wW . ctxT^T + bW  — both batches in one dispatch
    gemm_nt<3><<<dim3(50, 4, 2), 256, 0, stream>>>(wWb, ctxT, out, 256, 256, 256, 6400,
                                                   0, 1638400, 3276800, bW, nullptr);
}

// Round 6
// 309.495 us; speedup vs baseline: 1.0925x; 1.0925x over previous
//
#include <hip/hip_runtime.h>
#include <stdint.h>

typedef __attribute__((ext_vector_type(8))) short bf16x8;
typedef __attribute__((ext_vector_type(4))) float f32x4;

__device__ __forceinline__ ushort f2bf(float f) {
    union { float f; uint32_t i; } v; v.f = f;
    uint32_t r = v.i + 0x7fff + ((v.i >> 16) & 1);
    return (ushort)(r >> 16);
}
__device__ __forceinline__ uint32_t cvtpk(float lo, float hi) {
    uint32_t r;
    asm("v_cvt_pk_bf16_f32 %0, %1, %2" : "=v"(r) : "v"(lo), "v"(hi));
    return r;
}

typedef unsigned int uint_as1 __attribute__((address_space(1)));
typedef unsigned int uint_as3 __attribute__((address_space(3)));
__device__ __forceinline__ void async16(const void* g, void* l) {
    __builtin_amdgcn_global_load_lds((const uint_as1*)g, (uint_as3*)l, 16, 0, 0);
}

// ---------------- small prep kernels ----------------

__global__ void cvt_f32_bf16(const float* __restrict__ in, ushort* __restrict__ out, int n) {
    int i = blockIdx.x * blockDim.x + threadIdx.x;
    if (i < n) out[i] = f2bf(in[i]);
}

__global__ void prep_bn(const float* __restrict__ bk, const float* __restrict__ gamma,
                        const float* __restrict__ beta, const float* __restrict__ rmean,
                        const float* __restrict__ rvar,
                        float* __restrict__ scaleA, float* __restrict__ shiftA) {
    int i = threadIdx.x;  // 256 threads, 1 block
    float s = gamma[i] * rsqrtf(rvar[i] + 1e-5f);
    scaleA[i] = 0.25f * s;                                // fold Ck^-0.5 = 1/16 as 0.25 per operand
    shiftA[i] = 0.25f * ((bk[i] - rmean[i]) * s + beta[i]);
}

// x [b][512][6400] f32  ->  Xt [b][6400][512] bf16
__global__ void transpose_cvt(const float* __restrict__ x, ushort* __restrict__ xt) {
    __shared__ float t[32][33];
    int b = blockIdx.z;
    int n0 = blockIdx.x * 32, c0 = blockIdx.y * 32;
    const float* xb = x + (size_t)b * 512 * 6400;
    ushort* xtb = xt + (size_t)b * 6400 * 512;
    int tx = threadIdx.x, ty = threadIdx.y;
    t[ty][tx] = xb[(size_t)(c0 + ty) * 6400 + n0 + tx];
    __syncthreads();
    xtb[(size_t)(n0 + ty) * 512 + c0 + tx] = f2bf(t[tx][ty]);
}

// ---------------- unified NT GEMM: C[i][j] = sum_k A[i][k]*B[j][k] ----------------
// 128x128 tile, 4 waves, BK=32. 3-buffer LDS rotation with 2-deep prefetch:
// counted s_waitcnt vmcnt(4) + raw s_barrier per K-step (never vmcnt(0) mid-loop).
// LDS quarter-swizzle (validated round 5: SQ_LDS_BANK_CONFLICT = 0): LDS slot
// (row, q) holds global quarter q ^ ((row%16)>>1 & 3); applied by pre-swizzling
// the GLOBAL source of global_load_lds (rule #21) and reading with the matching
// lane-constant offset. Epilogue repacks acc through LDS for full-line stores,
// bf16 packing via v_cvt_pk_bf16_f32.
// EPI 0: bf16 store raw
// EPI 1: bf16 store relu(acc*vec0[col] + vec1[col])   (col-affine, BN+ReLU for Kt)
// EPI 2: bf16 store acc + vec0[row]                   (row bias, V)
// EPI 3: f32  store acc + vec0[row]                   (row bias, final out)
// EPI 4: f32  store raw                               (split-K partials)
// EPI 5: bf16 store exp(acc); per-row partial sums -> rsum[blockIdx.x*6400+row]
template <int EPI>
__global__ __launch_bounds__(256) void gemm_nt(
    const ushort* __restrict__ A, const ushort* __restrict__ B, void* __restrict__ Cout,
    int K, int lda, int ldb, int ldc,
    size_t zsa, size_t zsb, size_t zsc,
    const float* __restrict__ vec0, const float* __restrict__ vec1,
    float* __restrict__ rsum) {
    // [ A buf0|buf1|buf2 | B buf0|buf1|buf2 ], each 128x32 bf16 = 8 KB; total 48 KB
    __shared__ __align__(16) ushort smem[6 * 4096];

    A += (size_t)blockIdx.z * zsa;
    B += (size_t)blockIdx.z * zsb;

    const int tid = threadIdx.x;
    const int lane = tid & 63, wave = tid >> 6;
    const int wm = wave & 1, wn = wave >> 1;
    const int bM = blockIdx.y * 128, bN = blockIdx.x * 128;

    // staging: each wave loads 32 rows of A-tile and B-tile; one async16 = 16 rows x 32 bf16
    const int sr = lane >> 2;                              // row 0..15 within 16-row group
    const int scs = ((lane & 3) ^ ((lane >> 3) & 3)) * 8;  // swizzled source quarter
    const ushort* gA0 = A + (size_t)(bM + wave * 32 + sr) * lda + scs;
    const ushort* gA1 = gA0 + (size_t)16 * lda;
    const ushort* gB0 = B + (size_t)(bN + wave * 32 + sr) * ldb + scs;
    const ushort* gB1 = gB0 + (size_t)16 * ldb;
    ushort* lAw = &smem[wave * 1024];              // + buf*4096
    ushort* lBw = &smem[3 * 4096 + wave * 1024];   // + buf*4096

    const int rowA = wm * 64;          // wave's frag row base in LDS A
    const int rowB = wn * 64;
    const int fr = lane & 15;          // row within 16x16 tile
    const int fk = ((lane >> 4) ^ ((fr >> 1) & 3)) * 8;   // swizzled quarter read

    f32x4 acc[4][4] = {};
    const int nT = K >> 5;

    auto stage = [&](int t, int buf) {
        const int k0 = t * 32;
        const int ob = buf * 4096;
        async16(gA0 + k0, lAw + ob);
        async16(gA1 + k0, lAw + ob + 512);
        async16(gB0 + k0, lBw + ob);
        async16(gB1 + k0, lBw + ob + 512);
    };

    // prologue: stage tiles 0 and 1 (8 loads in flight)
    stage(0, 0);
    if (nT > 1) stage(1, 1);

    for (int t = 0; t < nT; ++t) {
        // tile t ready once its 4 loads complete; keep tile t+1's 4 in flight
        if (t + 1 < nT) { asm volatile("s_waitcnt vmcnt(4)" ::: "memory"); }
        else            { asm volatile("s_waitcnt vmcnt(0)" ::: "memory"); }
        __builtin_amdgcn_sched_barrier(0);
        __builtin_amdgcn_s_barrier();
        __builtin_amdgcn_sched_barrier(0);
        // buf (t+2)%3 == buf (t-1)%3: all reads of it finished before the barrier
        if (t + 2 < nT) stage(t + 2, (t + 2) % 3);
        const int cur = t % 3;
        const ushort* lA = &smem[cur * 4096];
        const ushort* lB = &smem[3 * 4096 + cur * 4096];
        bf16x8 af[4], bff[4];
#pragma unroll
        for (int mi = 0; mi < 4; mi++)
            af[mi] = *(const bf16x8*)&lA[(rowA + mi * 16 + fr) * 32 + fk];
#pragma unroll
        for (int ni = 0; ni < 4; ni++)
            bff[ni] = *(const bf16x8*)&lB[(rowB + ni * 16 + fr) * 32 + fk];
#pragma unroll
        for (int mi = 0; mi < 4; mi++)
#pragma unroll
            for (int ni = 0; ni < 4; ni++)
                acc[mi][ni] = __builtin_amdgcn_mfma_f32_16x16x32_bf16(af[mi], bff[ni], acc[mi][ni], 0, 0, 0);
        __builtin_amdgcn_sched_barrier(0);
    }
    // all LDS reads done before epilogue aliases smem as lt
    __builtin_amdgcn_s_barrier();
    __builtin_amdgcn_sched_barrier(0);

    // ---- epilogue: repack through LDS, store full lines ----
    float* Cf = (float*)Cout + (size_t)blockIdx.z * zsc;
    ushort* Cu = (ushort*)Cout + (size_t)blockIdx.z * zsc;
    float* lt = (float*)smem;          // 32*132*4 = 16896 B, fits in 48 KB
    const int g4 = (lane >> 4) * 4;
    const int cl = lane & 15;
    const int lr = tid >> 3;           // reader: LDS row 0..31
    const int ch = tid & 7;            // reader: 16-col chunk 0..7

#pragma unroll
    for (int mi = 0; mi < 4; ++mi) {
#pragma unroll
        for (int ni = 0; ni < 4; ++ni) {
            const int lcol = wn * 64 + ni * 16 + cl;
#pragma unroll
            for (int r = 0; r < 4; ++r)
                lt[(wm * 16 + g4 + r) * 132 + lcol] = acc[mi][ni][r];
        }
        __syncthreads();
        {
            const int brow = (lr < 16) ? (mi * 16 + lr) : (64 + mi * 16 + (lr - 16));
            const int grow = bM + brow;
            const int gcol = bN + ch * 16;
            float vv[16];
#pragma unroll
            for (int i = 0; i < 16; i += 4) {
                f32x4 q = *(const f32x4*)&lt[lr * 132 + ch * 16 + i];
                vv[i] = q[0]; vv[i + 1] = q[1]; vv[i + 2] = q[2]; vv[i + 3] = q[3];
            }
            if (EPI == 1) {
#pragma unroll
                for (int i = 0; i < 16; i++)
                    vv[i] = fmaxf(vv[i] * vec0[gcol + i] + vec1[gcol + i], 0.f);
            }
            if (EPI == 2 || EPI == 3) {
                const float rb = vec0[grow];
#pragma unroll
                for (int i = 0; i < 16; i++) vv[i] += rb;
            }
            if (EPI == 5) {
                float ssum = 0.f;
#pragma unroll
                for (int i = 0; i < 16; i++) { vv[i] = __expf(vv[i]); ssum += vv[i]; }
                // 8 threads (ch 0..7) hold the same row in consecutive lanes
                ssum += __shfl_down(ssum, 4, 8);
                ssum += __shfl_down(ssum, 2, 8);
                ssum += __shfl_down(ssum, 1, 8);
                if (ch == 0) rsum[(size_t)blockIdx.x * 6400 + grow] = ssum;
            }
            if (EPI == 3 || EPI == 4) {
#pragma unroll
                for (int i = 0; i < 16; i += 4) {
                    f32x4 q = { vv[i], vv[i + 1], vv[i + 2], vv[i + 3] };
                    *(f32x4*)&Cf[(size_t)grow * ldc + gcol + i] = q;
                }
            } else {
                uint4 q0 = { cvtpk(vv[0], vv[1]), cvtpk(vv[2], vv[3]),
                             cvtpk(vv[4], vv[5]), cvtpk(vv[6], vv[7]) };
                uint4 q1 = { cvtpk(vv[8], vv[9]), cvtpk(vv[10], vv[11]),
                             cvtpk(vv[12], vv[13]), cvtpk(vv[14], vv[15]) };
                *(uint4*)&Cu[(size_t)grow * ldc + gcol] = q0;
                *(uint4*)&Cu[(size_t)grow * ldc + gcol + 8] = q1;
            }
        }
        __syncthreads();   // lt free before next mi strip
    }
}

// ---------------- softmax normalizer: inv[row] = 1 / sum_xb rsum[xb][row] ----------------
__global__ __launch_bounds__(256) void combine_inv(const float* __restrict__ rsum,
                                                   float* __restrict__ inv) {
    int r = blockIdx.x * 256 + threadIdx.x;   // 6400 rows
    float s = 0.f;
#pragma unroll
    for (int xb = 0; xb < 50; xb++) s += rsum[(size_t)xb * 6400 + r];
    inv[r] = 1.f / s;
}

// ---------------- split-K reduce: ctxT bf16 = inv[row] * sum of 5 f32 partial chunks ----------------
__global__ __launch_bounds__(256) void reduce_ctx(const float* __restrict__ part, ushort* __restrict__ ctx,
                                                  const float* __restrict__ inv) {
    const size_t CH = 1638400;  // elems per chunk
    size_t i = ((size_t)blockIdx.x * 256 + threadIdx.x) * 4;
    float4 a = *(const float4*)&part[i];
#pragma unroll
    for (int c = 1; c < 5; c++) {
        float4 s = *(const float4*)&part[i + (size_t)c * CH];
        a.x += s.x; a.y += s.y; a.z += s.z; a.w += s.w;
    }
    const float w = inv[i >> 8];  // 256 cols per row; 4 consecutive elems share a row
    uint2 o = { cvtpk(a.x * w, a.y * w), cvtpk(a.z * w, a.w * w) };
    *(uint2*)&ctx[i] = o;
}

// ---------------- host ----------------
extern "C" void kernel_launch(void* const* d_in, const int* in_sizes, int n_in,
                              void* d_out, int out_size, void* d_ws, size_t ws_size,
                              hipStream_t stream) {
    (void)in_sizes; (void)n_in; (void)out_size; (void)ws_size;
    const float* x     = (const float*)d_in[0];
    const float* wk    = (const float*)d_in[1];
    const float* bk    = (const float*)d_in[2];
    const float* gamma = (const float*)d_in[3];
    const float* beta  = (const float*)d_in[4];
    const float* rmean = (const float*)d_in[5];
    const float* rvar  = (const float*)d_in[6];
    const float* wv    = (const float*)d_in[7];
    const float* bv    = (const float*)d_in[8];
    const float* wW    = (const float*)d_in[9];
    const float* bW    = (const float*)d_in[10];
    float* out = (float*)d_out;

    // workspace layout (ushort elements)
    ushort* Xt   = (ushort*)d_ws;          // 2*6400*512   = 6,553,600
    ushort* wkb  = Xt + 6553600;           // 256*512      = 131,072
    ushort* wvb  = wkb + 131072;           // 131,072
    ushort* wWb  = wvb + 131072;           // 512*256      = 131,072
    ushort* Kt   = wWb + 131072;           // 2*6400*256   = 3,276,800
    ushort* V    = Kt + 3276800;           // 3,276,800
    ushort* ctxT = V + 3276800;            // 3,276,800
    ushort* S    = ctxT + 3276800;         // 6400*6400    = 40,960,000 (one batch, reused)
    float* scaleA = (float*)(S + 40960000);
    float* shiftA = scaleA + 256;
    float* rowsum = shiftA + 256;          // 50*6400      = 320,000 f32
    float* inv    = rowsum + 320000;       // 6400 f32
    float* part   = inv + 6400;            // 5*6400*256 f32 = 8,192,000 f32 (33 MB)
    // total ~150 MB

    cvt_f32_bf16<<<512, 256, 0, stream>>>(wk, wkb, 131072);
    cvt_f32_bf16<<<512, 256, 0, stream>>>(wv, wvb, 131072);
    cvt_f32_bf16<<<512, 256, 0, stream>>>(wW, wWb, 131072);
    prep_bn<<<1, 256, 0, stream>>>(bk, gamma, beta, rmean, rvar, scaleA, shiftA);
    transpose_cvt<<<dim3(200, 16, 2), dim3(32, 32), 0, stream>>>(x, Xt);

    // Kt[b][n][ck] = relu(affine(Xt . wk^T)), scaled by 0.25  — both batches in one dispatch
    gemm_nt<1><<<dim3(2, 50, 2), 256, 0, stream>>>(Xt, wkb, Kt, 512, 512, 512, 256,
                                                   3276800, 0, 1638400, scaleA, shiftA, nullptr);
    // V[b][v][m] = wv . Xt^T + bv
    gemm_nt<2><<<dim3(50, 2, 2), 256, 0, stream>>>(wvb, Xt, V, 512, 512, 512, 6400,
                                                   0, 3276800, 1638400, bv, nullptr, nullptr);

    for (int b = 0; b < 2; b++) {
        ushort* Ktb  = Kt + (size_t)b * 1638400;
        ushort* Vb   = V  + (size_t)b * 1638400;
        ushort* ctxb = ctxT + (size_t)b * 1638400;
        // P_unnorm[n][m] = exp(Kt . Kt^T) (logits already include 1/16); row sums to rowsum
        gemm_nt<5><<<dim3(50, 50), 256, 0, stream>>>(Ktb, Ktb, S, 256, 256, 256, 6400,
                                                     0, 0, 0, nullptr, nullptr, rowsum);
        combine_inv<<<25, 256, 0, stream>>>(rowsum, inv);
        // ctxT[n][v] = P_unnorm . V^T — split-K x5 into f32 partials (z = k-chunk of 1280)
        gemm_nt<4><<<dim3(2, 50, 5), 256, 0, stream>>>(S, Vb, part, 1280, 6400, 6400, 256,
                                                       1280, 1280, 1638400, nullptr, nullptr, nullptr);
        reduce_ctx<<<1600, 256, 0, stream>>>(part, ctxb, inv);
    }

    // out[b][o][n] = wW . ctxT^T + bW  — both batches in one dispatch
    gemm_nt<3><<<dim3(50, 4, 2), 256, 0, stream>>>(wWb, ctxT, out, 256, 256, 256, 6400,
                                                   0, 1638400, 3276800, bW, nullptr, nullptr);
}